// Round 3
// baseline (192.517 us; speedup 1.0000x reference)
//
#include <hip/hip_runtime.h>
#include <math.h>

// Problem constants (fixed by reference)
#define BATCH        32768
#define IN_CH        512
#define NP           17     // NUM_POINTS
#define NSTEP        3

// Native vector type: HIP's float4 is a struct, which the nontemporal
// builtins reject; ext_vector_type is accepted.
typedef float fvec4 __attribute__((ext_vector_type(4)));

// Each thread: 1 float4 of data (4 input channels) -> 8 output floats.
// Total float4s = 32768*512/4 = 4,194,304 = 16384 blocks * 256 threads.

__global__ __launch_bounds__(256) void mac_kernel(
    const float* __restrict__ data,
    const float* __restrict__ angles,
    const float* __restrict__ velocity,
    const float* __restrict__ attention,
    const float* __restrict__ coeffp,
    const float* __restrict__ biasp,
    float* __restrict__ out)
{
    // Fused slope/intercept table: tab[j] = {v[j], a[j], v[j+1]-v[j], a[j+1]-a[j]}
    // with j+1 taken mod 17 (matches the reference's negative-index wrap:
    // ie == (ib+1) % 17 on the normal path for ALL reachable bgn in [-8, 9]).
    // One ds_read_b128 per eval replaces two ds_read_b64 gathers.
    __shared__ fvec4 tab[NP];
    const int tid = threadIdx.x;
    if (tid < NP) {
        int jn = tid + 1; if (jn == NP) jn = 0;
        float v0 = velocity[tid], a0 = angles[tid];
        fvec4 e; e.x = v0; e.y = a0; e.z = velocity[jn] - v0; e.w = angles[jn] - a0;
        tab[tid] = e;
    }
    const float coeff = coeffp[0];
    const float bias  = biasp[0];
    __syncthreads();

    const int gid = blockIdx.x * 256 + tid;        // float4 index into data
    const fvec4 d4 = __builtin_nontemporal_load((const fvec4*)data + gid);
    float x[4] = {d4.x, d4.y, d4.z, d4.w};

    const float INV3 = 0.33333333333333333f;       // 1/NUM_STEPS

    #pragma unroll
    for (int s = 0; s < NSTEP; ++s) {
        #pragma unroll
        for (int k = 0; k < 4; ++k) {
            float dv = x[k];
            float t = fmaf(dv, coeff, bias);
            float u = __expf(t + t);               // e^{2t}; overflow->inf is safe:
            // index = 1 + tanh(t)*8.5 = 9.5 - 17/(u+1)
            // u->inf => index->9.5 (pos->0.5), u->0 => index->-7.5 (pos->0.5):
            // both match the reference's saturated tanh(=+-1.0) exactly, so no clamp.
            float index = fmaf(-17.0f, __builtin_amdgcn_rcpf(u + 1.0f), 9.5f);

            float fb  = floorf(index);
            int   bgn = (int)fb;
            int   ib  = bgn + ((bgn >> 31) & NP);  // torch-style negative wrap
            float pos = index - fb;

            fvec4 tb   = tab[ib];
            float velo = fmaf(pos, tb.z, tb.x);    // v[ib] + pos*(v[ib+1]-v[ib])
            float ang  = fmaf(pos, tb.w, tb.y);

            // Reference computes end = floor(index+1.0), which on rare
            // float-boundary inputs equals bgn+2 (a genuine O(1) discontinuity
            // we must replicate). Exec-masked fixup, ~never taken.
            float fe = floorf(index + 1.0f);
            if (__builtin_expect(fe != fb + 1.0f, 0)) {
                int end = (int)fe;                 // end <= 10 < NP always
                int ie  = end + ((end >> 31) & NP);
                fvec4 te  = tab[ie];
                float om  = 1.0f - pos;
                velo = fmaf(om, tb.x, pos * te.x);
                ang  = fmaf(om, tb.y, pos * te.y);
            }

            float sn = __sinf(ang);                // ang in [0, 2pi]
            float cs = __cosf(ang);
            float stp = velo * fmaf(dv, sn, cs);   // velo*(cos + d*sin)
            x[k] = fmaf(stp, INV3, x[k]);
        }
    }

    // Output mapping: data element (b, c) -> out[b*1024 + 2c + {0,1}]
    const int b  = gid >> 7;          // gid / (512/4)
    const int c4 = gid & 127;
    const fvec4* attv = (const fvec4*)attention;
    const fvec4 a0 = attv[c4 * 2];
    const fvec4 a1 = attv[c4 * 2 + 1];

    fvec4 o0; o0.x = a0.x * x[0]; o0.y = a0.y * x[0]; o0.z = a0.z * x[1]; o0.w = a0.w * x[1];
    fvec4 o1; o1.x = a1.x * x[2]; o1.y = a1.y * x[2]; o1.z = a1.z * x[3]; o1.w = a1.w * x[3];

    fvec4* outv = (fvec4*)out;
    const int base = b * 256 + c4 * 2;            // float4 index into out
    __builtin_nontemporal_store(o0, outv + base);
    __builtin_nontemporal_store(o1, outv + base + 1);
}

extern "C" void kernel_launch(void* const* d_in, const int* in_sizes, int n_in,
                              void* d_out, int out_size, void* d_ws, size_t ws_size,
                              hipStream_t stream) {
    const float* data      = (const float*)d_in[0];
    const float* angles    = (const float*)d_in[1];
    const float* velocity  = (const float*)d_in[2];
    const float* attention = (const float*)d_in[3];
    const float* coeff     = (const float*)d_in[4];
    const float* bias      = (const float*)d_in[5];
    float* out = (float*)d_out;

    const int total_f4 = BATCH * IN_CH / 4;       // 4,194,304
    const int block = 256;
    const int grid  = total_f4 / block;           // 16384
    mac_kernel<<<grid, block, 0, stream>>>(data, angles, velocity, attention,
                                           coeff, bias, out);
}